// Round 7
// baseline (300.516 us; speedup 1.0000x reference)
//
#include <hip/hip_runtime.h>
#include <hip/hip_bf16.h>
#include <cstdint>
#include <cstddef>

// BaseNet: B=262144 samples, d=512.
// H = relu(reshape(combined,[2B,512]) @ W_in + b_in)   [2B,128]
// m[s] = 0.5*(H[2s]+H[2s+1])                           [B,128]
// g1 = relu(m @ W1 + b1); g2 = relu(g1 @ W2 + b2)      [B,128],[B,64]
// out = sigmoid(g2 . (W_out[:64]+W_out[64:]) + b_out)  [B]
//
// Round-7 theory: main-GEMM BW capped at ~4.5 TB/s by DRAM page thrash from
// 16-row-strided 64-128B A-loads (256 streams/CU). Harness fills prove 6.5 TB/s
// at 10.7% occupancy with SEQUENTIAL streams. Fix: loader waves read 2KB
// contiguous, bf16-cvt in regs, scatter into XOR-swizzled LDS A-tile; MFMA
// frags read from LDS (standard k-mapping). 32 streams/CU, 512B/page-visit.

#define NROWS   524288   // 2B
#define NSAMP   262144   // B

typedef __attribute__((ext_vector_type(8))) short  bf16x8;
typedef __attribute__((ext_vector_type(4))) float  f32x4;
typedef __attribute__((ext_vector_type(2))) unsigned int u32x2;

#define LGKM0() asm volatile("s_waitcnt lgkmcnt(0)" ::: "memory")
#define VMW2()  asm volatile("s_waitcnt vmcnt(2)" ::: "memory")
#define VMW0()  asm volatile("s_waitcnt vmcnt(0)" ::: "memory")
#define BAR()   __builtin_amdgcn_s_barrier()

__device__ __forceinline__ unsigned short f2bf(float f) {
    unsigned u = __float_as_uint(f);
    u += 0x7fffu + ((u >> 16) & 1u);   // round-to-nearest-even
    return (unsigned short)(u >> 16);
}

__device__ __forceinline__ f32x4 mfma16(bf16x8 a, bf16x8 b, f32x4 c) {
    return __builtin_amdgcn_mfma_f32_16x16x32_bf16(a, b, c, 0, 0, 0);
}

// f32x4 -> 8B bf16 (RNE, packed) -> LDS
__device__ __forceinline__ void cvtwr8(char* dst, f32x4 v) {
    unsigned a, b;
    asm("v_cvt_pk_bf16_f32 %0, %1, %2" : "=v"(a) : "v"(v[0]), "v"(v[1]));
    asm("v_cvt_pk_bf16_f32 %0, %1, %2" : "=v"(b) : "v"(v[2]), "v"(v[3]));
    u32x2 p; p[0] = a; p[1] = b;
    *(u32x2*)dst = p;
}

// ---------------- workspace layout (bytes) ----------------
#define WS_M     0                       // [B][128] bf16 = 67108864 B
#define WS_WIN   67108864                // Win frags: 16*8*64*8 bf16 = 131072 B
#define WS_W1    67239936                // W1 frags:  4*8*64*8 bf16 = 32768 B
#define WS_W2    67272704                // W2 frags:  4*4*64*8 bf16 = 16384 B
#define WS_WEFF  67289088                // 64 floats

// ---------------- prep: pack weights to MFMA B-fragment layout --------------
// ALL standard now (kA reads A-frags from LDS, so no k-permutation needed):
// frag (kt, n): lane l slot j holds W[kt*32 + (l>>4)*8 + j][n*16 + (l&15)].
__global__ void prep_kernel(const float* __restrict__ W_in,
                            const float* __restrict__ W1,
                            const float* __restrict__ W2,
                            const float* __restrict__ W_out,
                            unsigned short* __restrict__ fWin,
                            unsigned short* __restrict__ fW1,
                            unsigned short* __restrict__ fW2,
                            float* __restrict__ weff) {
    int tid = blockIdx.x * 256 + threadIdx.x;
    if (tid < 65536) {                       // W_in [512][128]: KT=16, NT=8
        int e = tid;
        int j = e & 7, l = (e >> 3) & 63, rest = e >> 9;
        int n = rest & 7, kt = rest >> 3;
        int k = kt * 32 + ((l >> 4) << 3) + j;
        int col = n * 16 + (l & 15);
        fWin[e] = f2bf(W_in[k * 128 + col]);
    } else if (tid < 65536 + 16384) {        // W1 [128][128]: KT=4, NT=8
        int e = tid - 65536;
        int j = e & 7, l = (e >> 3) & 63, rest = e >> 9;
        int n = rest & 7, kt = rest >> 3;
        int k = kt * 32 + ((l >> 4) << 3) + j;
        int col = n * 16 + (l & 15);
        fW1[e] = f2bf(W1[k * 128 + col]);
    } else if (tid < 65536 + 16384 + 8192) { // W2 [128][64]: KT=4, NT=4
        int e = tid - 65536 - 16384;
        int j = e & 7, l = (e >> 3) & 63, rest = e >> 9;
        int n = rest & 3, kt = rest >> 2;
        int k = kt * 32 + ((l >> 4) << 3) + j;
        int col = n * 16 + (l & 15);
        fW2[e] = f2bf(W2[k * 64 + col]);
    } else if (tid < 65536 + 16384 + 8192 + 64) {
        int c = tid - (65536 + 16384 + 8192);
        weff[c] = W_out[c] + W_out[64 + c];
    }
}

// ---------------- kernel A: GEMM + bias/relu + node-mean -> M (bf16) --------
// 256 blocks x 512 thr (8 waves, 2/EU, waves_per_eu(2,2) pins 256-VGPR budget).
// Per block: 64 tiles of BM=32 rows; per tile 4 stages of BK=128.
// Wave (rg = w>>2, q = w&3) computes rows rg*16..+16, cols {2q,2q+1}*16.
// Staging: each wave loads 2x1KB CONTIGUOUS (rows w*4..w*4+3 x 512B k-slice),
// cvt to bf16, ds_write_b64 scatter into swizzled LDS [32 r][256 B]
// (byte ^= (r&7)<<4). Depth-2 reg pipeline + LDS dbuf; raw s_barrier with
// per-wave lgkmcnt(0) and COUNTED vmcnt(2) (loads span stages, never drained).
// LDS: 128K W_in frags + 2x8K A + 4K bounce = 148 KB.
__global__ void __launch_bounds__(512) __attribute__((amdgpu_waves_per_eu(2, 2)))
kA(const float* __restrict__ A,              // [2B][512] fp32 (= combined)
   const unsigned short* __restrict__ fWin,
   const float* __restrict__ b_in,
   unsigned short* __restrict__ M) {         // [B][128] bf16
    __shared__ __align__(16) unsigned short lds[75776];  // 148 KB
    char* ldsb = (char*)lds;
    char* buf0 = ldsb + 131072;   // A stage ping (8 KB)
    char* buf1 = ldsb + 139264;   // A stage pong (8 KB)
    char* bounce = ldsb + 147456; // m bounce (4 KB = 16 samples x 256 B)
    {
        const f32x4* src = (const f32x4*)fWin;
        f32x4* dst = (f32x4*)lds;
        int tid = threadIdx.x;
        #pragma unroll
        for (int i = 0; i < 16; ++i) dst[i * 512 + tid] = src[i * 512 + tid];
    }
    __syncthreads();

    const int w = threadIdx.x >> 6, l = threadIdx.x & 63;
    const int r16 = l & 15, lg = l >> 4;
    const int rg = w >> 2, q = w & 3;

    // ---- loader geometry: wave w owns rows w*4..w*4+3 of the 32-row stage.
    const int lsub = l >> 5;                 // 0/1: which row within the pair
    const int lcol = (l & 31) * 4;           // float offset within 128-float slice
    const int row0 = w * 4 + lsub;           // instr 0 rows
    const int row1 = w * 4 + 2 + lsub;       // instr 1 rows
    const int boff0 = row0 * 512 + lcol;     // global float offset within tile
    const int boff1 = row1 * 512 + lcol;
    // LDS write offsets (bf16, swizzled): row*256 + ((l&31)*8 ^ ((row&7)<<4))
    const int woff0 = row0 * 256 + ((((l & 31) * 8)) ^ ((row0 & 7) << 4));
    const int woff1 = row1 * 256 + ((((l & 31) * 8)) ^ ((row1 & 7) << 4));

    // ---- MFMA-side geometry
    const int r = rg * 16 + r16;             // A row this lane supplies
    const int ro0 = r * 256 + (((0 * 64 + lg * 16)) ^ ((r & 7) << 4));
    const int ro1 = r * 256 + (((1 * 64 + lg * 16)) ^ ((r & 7) << 4));
    const int ro2 = r * 256 + (((2 * 64 + lg * 16)) ^ ((r & 7) << 4));
    const int ro3 = r * 256 + (((3 * 64 + lg * 16)) ^ ((r & 7) << 4));
    const int n0 = 2 * q, n1 = 2 * q + 1;
    const int bB0 = n0 * 1024 + l * 16;      // byte offset within kt-block (8192 B)
    const int bB1 = n1 * 1024 + l * 16;
    const float bb0 = b_in[n0 * 16 + r16];
    const float bb1 = b_in[n1 * 16 + r16];
    // bounce write offsets: sample_local = rg*8 + lg*2 (+jp), col = n*16+r16
    const int sb = (rg * 8 + lg * 2) * 256;
    const int bo00 = sb + (n0 * 16 + r16) * 2,  bo01 = bo00 + 256;
    const int bo10 = sb + (n1 * 16 + r16) * 2,  bo11 = bo10 + 256;

    const float* Abase = A + (size_t)blockIdx.x * 2048 * 512;

    f32x4 r0a, r0b, r1a, r1b;  // depth-2 reg staging (parity 0 / parity 1)
    f32x4 acc0, acc1;

    #define LADDR(t, s, bo) (Abase + (size_t)(t) * 16384 + (bo) + (s) * 128)
    #define ISSUE0(t, s) { r0a = *(const f32x4*)LADDR(t, s, boff0); \
                           r0b = *(const f32x4*)LADDR(t, s, boff1); }
    #define ISSUE1(t, s) { r1a = *(const f32x4*)LADDR(t, s, boff0); \
                           r1b = *(const f32x4*)LADDR(t, s, boff1); }
    #define CVT0(buf) { cvtwr8((buf) + woff0, r0a); cvtwr8((buf) + woff1, r0b); }
    #define CVT1(buf) { cvtwr8((buf) + woff0, r1a); cvtwr8((buf) + woff1, r1b); }
    #define STAGE(s, buf) { \
        _Pragma("unroll") \
        for (int kg = 0; kg < 4; ++kg) { \
            const int rof = (kg == 0) ? ro0 : (kg == 1) ? ro1 : (kg == 2) ? ro2 : ro3; \
            bf16x8 af = *(const bf16x8*)((buf) + rof); \
            const char* wb = ldsb + ((s) * 4 + kg) * 8192; \
            bf16x8 bf0v = *(const bf16x8*)(wb + bB0); \
            bf16x8 bf1v = *(const bf16x8*)(wb + bB1); \
            acc0 = mfma16(af, bf0v, acc0); \
            acc1 = mfma16(af, bf1v, acc1); \
        } }
    #define EPI() { \
        float h0 = fmaxf(acc0[0] + bb0, 0.f), h1 = fmaxf(acc0[1] + bb0, 0.f); \
        float h2 = fmaxf(acc0[2] + bb0, 0.f), h3 = fmaxf(acc0[3] + bb0, 0.f); \
        *(unsigned short*)(bounce + bo00) = f2bf(0.5f * (h0 + h1)); \
        *(unsigned short*)(bounce + bo01) = f2bf(0.5f * (h2 + h3)); \
        float g0 = fmaxf(acc1[0] + bb1, 0.f), g1 = fmaxf(acc1[1] + bb1, 0.f); \
        float g2 = fmaxf(acc1[2] + bb1, 0.f), g3 = fmaxf(acc1[3] + bb1, 0.f); \
        *(unsigned short*)(bounce + bo10) = f2bf(0.5f * (g0 + g1)); \
        *(unsigned short*)(bounce + bo11) = f2bf(0.5f * (g2 + g3)); }
    #define MSTORE(t) if (w < 4) { \
        bf16x8 v = *(const bf16x8*)(bounce + w * 1024 + l * 16); \
        *(bf16x8*)&M[((size_t)blockIdx.x * 1024 + (t) * 16 + w * 4 + lg) * 128 + r16 * 8] = v; }

    // ---- prologue: stages (0,0) and (0,1)
    ISSUE0(0, 0);
    ISSUE1(0, 1);
    VMW2();                 // stage (0,0) arrived
    CVT0(buf0);
    LGKM0(); BAR();

    for (int t = 0; t < 63; ++t) {
        acc0 = (f32x4){0.f, 0.f, 0.f, 0.f};
        acc1 = (f32x4){0.f, 0.f, 0.f, 0.f};
        // s=0 (parity 0): compute buf0; cvt stage +1 (parity1); issue +2 (parity0)
        STAGE(0, buf0);
        ISSUE0(t, 2);
        VMW2(); CVT1(buf1);
        LGKM0(); BAR();
        // s=1
        STAGE(1, buf1);
        ISSUE1(t, 3);
        VMW2(); CVT0(buf0);
        LGKM0(); BAR();
        // s=2
        STAGE(2, buf0);
        ISSUE0(t + 1, 0);
        VMW2(); CVT1(buf1);
        LGKM0(); BAR();
        // s=3 + epilogue
        STAGE(3, buf1);
        EPI();
        ISSUE1(t + 1, 1);
        VMW2(); CVT0(buf0);
        LGKM0(); BAR();
        MSTORE(t);
    }
    // ---- tail tile t = 63
    {
        acc0 = (f32x4){0.f, 0.f, 0.f, 0.f};
        acc1 = (f32x4){0.f, 0.f, 0.f, 0.f};
        STAGE(0, buf0);
        ISSUE0(63, 2);
        VMW2(); CVT1(buf1);
        LGKM0(); BAR();
        STAGE(1, buf1);
        ISSUE1(63, 3);
        VMW2(); CVT0(buf0);
        LGKM0(); BAR();
        STAGE(2, buf0);
        VMW0(); CVT1(buf1);   // last stage: drain fully
        LGKM0(); BAR();
        STAGE(3, buf1);
        EPI();
        LGKM0(); BAR();
        MSTORE(63);
    }
    #undef LADDR
    #undef ISSUE0
    #undef ISSUE1
    #undef CVT0
    #undef CVT1
    #undef STAGE
    #undef EPI
    #undef MSTORE
}

// ---------------- kernel B: m -> g1 -> g2 -> sigmoid(score) -----------------
// 512 blocks (2/CU, LDS=52KB), 4 waves x 16 samples per tile-iter. (round-4)
__global__ void __launch_bounds__(256, 2)
kB(const unsigned short* __restrict__ M,
   const unsigned short* __restrict__ fW1,
   const unsigned short* __restrict__ fW2,
   const float* __restrict__ weff,
   const float* __restrict__ b1,
   const float* __restrict__ b2,
   const float* __restrict__ b_out,
   float* __restrict__ out) {
    __shared__ unsigned short lw1[16384];       // 32 KB
    __shared__ unsigned short lw2[8192];        // 16 KB
    __shared__ unsigned short bounce[4][2048];  // 4 waves x 4 KB
    {
        int tid = threadIdx.x;
        const f32x4* s1 = (const f32x4*)fW1;
        f32x4* d1 = (f32x4*)lw1;
        #pragma unroll
        for (int i = 0; i < 8; ++i) d1[i * 256 + tid] = s1[i * 256 + tid];
        const f32x4* s2 = (const f32x4*)fW2;
        f32x4* d2 = (f32x4*)lw2;
        #pragma unroll
        for (int i = 0; i < 4; ++i) d2[i * 256 + tid] = s2[i * 256 + tid];
    }
    __syncthreads();
    const int w = threadIdx.x >> 6, l = threadIdx.x & 63;
    const int lr = l & 15, lg = l >> 4;
    float b1v[8], b2v[4], wev[4];
    #pragma unroll
    for (int n = 0; n < 8; ++n) b1v[n] = b1[n * 16 + lr];
    #pragma unroll
    for (int n = 0; n < 4; ++n) { b2v[n] = b2[n * 16 + lr]; wev[n] = weff[n * 16 + lr]; }
    const float bo = b_out[0];

    for (int t = blockIdx.x; t < NSAMP / 64; t += 512) {
        const int s0 = t * 64 + w * 16;
        f32x4 acc1[8];
        #pragma unroll
        for (int n = 0; n < 8; ++n) acc1[n] = (f32x4){0.f, 0.f, 0.f, 0.f};
        const unsigned short* arow = M + (size_t)(s0 + lr) * 128 + lg * 8;
        #pragma unroll
        for (int ks = 0; ks < 4; ++ks) {
            bf16x8 af = *(const bf16x8*)(arow + ks * 32);
            #pragma unroll
            for (int n = 0; n < 8; ++n) {
                bf16x8 bf = *(const bf16x8*)&lw1[((ks * 8 + n) * 64 + l) * 8];
                acc1[n] = __builtin_amdgcn_mfma_f32_16x16x32_bf16(af, bf, acc1[n], 0, 0, 0);
            }
        }
        #pragma unroll
        for (int n = 0; n < 8; ++n) {
            #pragma unroll
            for (int rr = 0; rr < 4; ++rr) {
                float g = fmaxf(acc1[n][rr] + b1v[n], 0.f);
                int row = lg * 4 + rr, col = n * 16 + lr;
                int boff = row * 256 + ((col * 2) ^ ((row & 7) << 4));
                bounce[w][boff >> 1] = f2bf(g);
            }
        }
        f32x4 acc2[4];
        #pragma unroll
        for (int n = 0; n < 4; ++n) acc2[n] = (f32x4){0.f, 0.f, 0.f, 0.f};
        #pragma unroll
        for (int ks = 0; ks < 4; ++ks) {
            int roff = lr * 256 + ((ks * 64 + lg * 16) ^ ((lr & 7) << 4));
            bf16x8 af2 = *(const bf16x8*)((const char*)&bounce[w][0] + roff);
            #pragma unroll
            for (int n = 0; n < 4; ++n) {
                bf16x8 bf = *(const bf16x8*)&lw2[((ks * 4 + n) * 64 + l) * 8];
                acc2[n] = __builtin_amdgcn_mfma_f32_16x16x32_bf16(af2, bf, acc2[n], 0, 0, 0);
            }
        }
        float p0 = 0.f, p1 = 0.f, p2 = 0.f, p3 = 0.f;
        #pragma unroll
        for (int n = 0; n < 4; ++n) {
            p0 += fmaxf(acc2[n][0] + b2v[n], 0.f) * wev[n];
            p1 += fmaxf(acc2[n][1] + b2v[n], 0.f) * wev[n];
            p2 += fmaxf(acc2[n][2] + b2v[n], 0.f) * wev[n];
            p3 += fmaxf(acc2[n][3] + b2v[n], 0.f) * wev[n];
        }
        #pragma unroll
        for (int m = 1; m < 16; m <<= 1) {
            p0 += __shfl_xor(p0, m);
            p1 += __shfl_xor(p1, m);
            p2 += __shfl_xor(p2, m);
            p3 += __shfl_xor(p3, m);
        }
        float s0f = 1.f / (1.f + expf(-(p0 + bo)));
        float s1f = 1.f / (1.f + expf(-(p1 + bo)));
        float s2f = 1.f / (1.f + expf(-(p2 + bo)));
        float s3f = 1.f / (1.f + expf(-(p3 + bo)));
        if (lr < 4) {
            float v = (lr == 0) ? s0f : (lr == 1) ? s1f : (lr == 2) ? s2f : s3f;
            out[s0 + lg * 4 + lr] = v;
        }
    }
}

// ---------------- host launcher ----------------
extern "C" void kernel_launch(void* const* d_in, const int* in_sizes, int n_in,
                              void* d_out, int out_size, void* d_ws, size_t ws_size,
                              hipStream_t stream) {
    const float* combined = (const float*)d_in[0];
    const float* W_in  = (const float*)d_in[1];
    const float* b_in  = (const float*)d_in[2];
    const float* W1    = (const float*)d_in[3];
    const float* b1    = (const float*)d_in[4];
    const float* W2    = (const float*)d_in[5];
    const float* b2    = (const float*)d_in[6];
    const float* W_out = (const float*)d_in[7];
    const float* b_out = (const float*)d_in[8];
    float* out = (float*)d_out;

    char* ws = (char*)d_ws;
    unsigned short* M    = (unsigned short*)(ws + WS_M);
    unsigned short* fWin = (unsigned short*)(ws + WS_WIN);
    unsigned short* fW1  = (unsigned short*)(ws + WS_W1);
    unsigned short* fW2  = (unsigned short*)(ws + WS_W2);
    float* weff          = (float*)(ws + WS_WEFF);

    prep_kernel<<<(65536 + 16384 + 8192 + 64 + 255) / 256, 256, 0, stream>>>(
        W_in, W1, W2, W_out, fWin, fW1, fW2, weff);
    kA<<<256, 512, 0, stream>>>(combined, fWin, b_in, M);
    kB<<<512, 256, 0, stream>>>(M, fW1, fW2, weff, b1, b2, b_out, out);
}

// Round 8
// 292.699 us; speedup vs baseline: 1.0267x; 1.0267x over previous
//
#include <hip/hip_runtime.h>
#include <hip/hip_bf16.h>
#include <cstdint>
#include <cstddef>

// BaseNet: B=262144 samples, d=512.
// H = relu(reshape(combined,[2B,512]) @ W_in + b_in)   [2B,128]
// m[s] = 0.5*(H[2s]+H[2s+1])                           [B,128]
// g1 = relu(m @ W1 + b1); g2 = relu(g1 @ W2 + b2)      [B,128],[B,64]
// out = sigmoid(g2 . (W_out[:64]+W_out[64:]) + b_out)  [B]
//
// Round-8: single controlled change vs R4 = occupancy 2->4 waves/SIMD.
// R4 (279us) / R6 (290) / R7 (300) all ran 2 waves/SIMD; harness fills prove
// the chip's BW needs stream depth, and our in-flight bytes/CU were marginal.
// Structure: R4's direct permuted-k register loads (64B segments/row, no
// A-staging LDS, no main-loop barriers), 1024 thr = 16 waves x 16 rows,
// waves_per_eu(4,4) pins 128 VGPR; ring-4 staging (32 VGPR) + cross-tile
// prefetch; per-wave LDS bounce for 1KB-contiguous M stores.

#define NROWS   524288   // 2B
#define NSAMP   262144   // B

typedef __attribute__((ext_vector_type(8))) short  bf16x8;
typedef __attribute__((ext_vector_type(4))) float  f32x4;

#define LGKM0() asm volatile("s_waitcnt lgkmcnt(0)" ::: "memory")

__device__ __forceinline__ unsigned short f2bf(float f) {
    unsigned u = __float_as_uint(f);
    u += 0x7fffu + ((u >> 16) & 1u);   // round-to-nearest-even
    return (unsigned short)(u >> 16);
}

// packed bf16 convert: 4x v_cvt_pk_bf16_f32 (RNE, same numerics as f2bf)
__device__ __forceinline__ bf16x8 cvt8(f32x4 lo, f32x4 hi) {
    union { unsigned u[4]; bf16x8 v; } r;
    asm("v_cvt_pk_bf16_f32 %0, %1, %2" : "=v"(r.u[0]) : "v"(lo[0]), "v"(lo[1]));
    asm("v_cvt_pk_bf16_f32 %0, %1, %2" : "=v"(r.u[1]) : "v"(lo[2]), "v"(lo[3]));
    asm("v_cvt_pk_bf16_f32 %0, %1, %2" : "=v"(r.u[2]) : "v"(hi[0]), "v"(hi[1]));
    asm("v_cvt_pk_bf16_f32 %0, %1, %2" : "=v"(r.u[3]) : "v"(hi[2]), "v"(hi[3]));
    return r.v;
}

__device__ __forceinline__ f32x4 mfma16(bf16x8 a, bf16x8 b, f32x4 c) {
    return __builtin_amdgcn_mfma_f32_16x16x32_bf16(a, b, c, 0, 0, 0);
}

// ---------------- workspace layout (bytes) ----------------
#define WS_M     0                       // [B][128] bf16 = 67108864 B
#define WS_WIN   67108864                // Win frags: 16*8*64*8 bf16 = 131072 B
#define WS_W1    67239936                // W1 frags:  4*8*64*8 bf16 = 32768 B
#define WS_W2    67272704                // W2 frags:  4*4*64*8 bf16 = 16384 B
#define WS_WEFF  67289088                // 64 floats

// ---------------- prep: pack weights to MFMA B-fragment layout ----------------
// Standard B-frag (16x16x32): lane l holds B[k=(l>>4)*8+j][col=l&15], j=0..7.
// fWin uses the PERMUTED k mapping matching kA's coalesced A loads:
//   slot j of lane (lg=l>>4): k = (j<4) ? lg*4+j : 16+lg*4+(j-4)  (within 32-group)
__global__ void prep_kernel(const float* __restrict__ W_in,
                            const float* __restrict__ W1,
                            const float* __restrict__ W2,
                            const float* __restrict__ W_out,
                            unsigned short* __restrict__ fWin,
                            unsigned short* __restrict__ fW1,
                            unsigned short* __restrict__ fW2,
                            float* __restrict__ weff) {
    int tid = blockIdx.x * 256 + threadIdx.x;
    if (tid < 65536) {                       // W_in [512][128]: KT=16, NT=8 (permuted k)
        int e = tid;
        int j = e & 7, l = (e >> 3) & 63, rest = e >> 9;
        int n = rest & 7, kt = rest >> 3;
        int lg = l >> 4;
        int kin = (j < 4) ? (lg * 4 + j) : (16 + lg * 4 + (j - 4));
        int k = kt * 32 + kin;
        int col = n * 16 + (l & 15);
        fWin[e] = f2bf(W_in[k * 128 + col]);
    } else if (tid < 65536 + 16384) {        // W1 [128][128]: KT=4, NT=8 (standard)
        int e = tid - 65536;
        int j = e & 7, l = (e >> 3) & 63, rest = e >> 9;
        int n = rest & 7, kt = rest >> 3;
        int k = kt * 32 + ((l >> 4) << 3) + j;
        int col = n * 16 + (l & 15);
        fW1[e] = f2bf(W1[k * 128 + col]);
    } else if (tid < 65536 + 16384 + 8192) { // W2 [128][64]: KT=4, NT=4 (standard)
        int e = tid - 65536 - 16384;
        int j = e & 7, l = (e >> 3) & 63, rest = e >> 9;
        int n = rest & 3, kt = rest >> 2;
        int k = kt * 32 + ((l >> 4) << 3) + j;
        int col = n * 16 + (l & 15);
        fW2[e] = f2bf(W2[k * 64 + col]);
    } else if (tid < 65536 + 16384 + 8192 + 64) {
        int c = tid - (65536 + 16384 + 8192);
        weff[c] = W_out[c] + W_out[64 + c];
    }
}

// ---------------- kernel A: GEMM + bias/relu + node-mean -> M (bf16) --------
// 256 blocks x 1024 thr = 16 waves (4/SIMD); amdgpu_waves_per_eu(4,4) pins the
// VGPR budget at 128 (LDS 160KB -> exactly 1 block/CU, 16 waves = 4/EU).
// Each wave owns 16 rows/tile; 8 tiles of 256 rows per block (contiguous 2048).
// A loads: permuted-k mapping -> each instr = 16 rows x 64B contiguous.
// Staging: 32-float chunks, ring of 4 (st[4][2] = 32 VGPR), prefetch distance
// 3 (~6KB/wave in flight x 16 waves = 96KB/CU); 16 chunks/tile, 16%4==0:
// chunks 13..15 prefetch the NEXT tile phase-aligned. No main-loop barriers.
// Epilogue: bias+relu+pair-mean -> per-wave 2KB LDS bounce -> 1KB M stores.
__global__ void __launch_bounds__(1024) __attribute__((amdgpu_waves_per_eu(4, 4)))
kA(const float* __restrict__ A,              // [2B][512] fp32 (= combined)
   const unsigned short* __restrict__ fWin,  // frag layout (permuted k)
   const float* __restrict__ b_in,
   unsigned short* __restrict__ M) {         // [B][128] bf16
    __shared__ __align__(16) unsigned short lds[81920];  // 160 KB exactly
    unsigned short* lwin = lds;                          // 131072 B: W_in frags
    {
        const f32x4* src = (const f32x4*)fWin;
        f32x4* dst = (f32x4*)lds;
        int tid = threadIdx.x;
        #pragma unroll
        for (int i = 0; i < 8; ++i) dst[i * 1024 + tid] = src[i * 1024 + tid];
    }
    __syncthreads();
    const int w = threadIdx.x >> 6, l = threadIdx.x & 63;
    const int lr = l & 15, lg = l >> 4;
    char* bw = (char*)lds + 131072 + w * 2048;           // per-wave 2KB bounce
    float binv[8];
    #pragma unroll
    for (int n = 0; n < 8; ++n) binv[n] = b_in[n * 16 + lr];

    const size_t NEXT = 131072;              // 256 rows * 512 floats
    const float* a0 = A + ((size_t)blockIdx.x * 2048 + (size_t)w * 16 + lr) * 512 + lg * 4;

    // staging ring: [buf][half], chunk = 32 floats of k (one 16x16x32 k-group)
    f32x4 st[4][2];
    #pragma unroll
    for (int pc = 0; pc < 3; ++pc) {
        st[pc][0] = *(const f32x4*)(a0 + pc * 32);
        st[pc][1] = *(const f32x4*)(a0 + pc * 32 + 16);
    }

    for (int i = 0; i < 8; ++i) {            // 8 tiles of 256 rows per block
        const size_t nextoff = (i == 7) ? 0 : NEXT;
        f32x4 acc[8];
        #pragma unroll
        for (int n = 0; n < 8; ++n) acc[n] = (f32x4){0.f, 0.f, 0.f, 0.f};

        #pragma unroll
        for (int c = 0; c < 16; ++c) {       // 16 k-chunks x 32 floats
            {   // prefetch chunk c+3 (chunks 13..15 target the next tile)
                const int nb = (c + 3) & 3;
                const float* q0 = (c < 13) ? (a0 + (c + 3) * 32)
                                           : (a0 + nextoff + (c - 13) * 32);
                st[nb][0] = *(const f32x4*)(q0);
                st[nb][1] = *(const f32x4*)(q0 + 16);
            }
            const int cb = c & 3;
            bf16x8 af = cvt8(st[cb][0], st[cb][1]);
            #pragma unroll
            for (int n = 0; n < 8; ++n) {
                bf16x8 bf = *(const bf16x8*)&lwin[((c * 8 + n) * 64 + l) * 8];
                acc[n] = mfma16(af, bf, acc[n]);
            }
        }

        // ---- epilogue: bias+relu+pair-mean -> bounce [8 samp][256B] ----
        // C layout: row=lg*4+r, col=lr; rows {4lg,4lg+1}->sample 2lg,
        // rows {4lg+2,4lg+3}->sample 2lg+1.
        #pragma unroll
        for (int n = 0; n < 8; ++n) {
            const float b = binv[n];
            float h0 = fmaxf(acc[n][0] + b, 0.f);
            float h1 = fmaxf(acc[n][1] + b, 0.f);
            float h2 = fmaxf(acc[n][2] + b, 0.f);
            float h3 = fmaxf(acc[n][3] + b, 0.f);
            int bo = (2 * lg) * 256 + (n * 16 + lr) * 2;
            *(unsigned short*)(bw + bo)       = f2bf(0.5f * (h0 + h1));
            *(unsigned short*)(bw + bo + 256) = f2bf(0.5f * (h2 + h3));
        }
        LGKM0();   // same-wave ds_write -> ds_read
        // readback 2KB contiguous, store 2x1KB lines to M
        const size_t sampbase = (size_t)blockIdx.x * 1024 + (size_t)i * 128 + (size_t)w * 8;
        #pragma unroll
        for (int r = 0; r < 2; ++r) {
            bf16x8 v = *(const bf16x8*)(bw + r * 1024 + l * 16);
            *(bf16x8*)&M[(sampbase + r * 4 + lg) * 128 + lr * 8] = v;
        }
        a0 += nextoff;
    }
}

// ---------------- kernel B: m -> g1 -> g2 -> sigmoid(score) -----------------
// 512 blocks (2/CU, LDS=52KB), 4 waves x 16 samples per tile-iter. (round-4)
__global__ void __launch_bounds__(256, 2)
kB(const unsigned short* __restrict__ M,
   const unsigned short* __restrict__ fW1,
   const unsigned short* __restrict__ fW2,
   const float* __restrict__ weff,
   const float* __restrict__ b1,
   const float* __restrict__ b2,
   const float* __restrict__ b_out,
   float* __restrict__ out) {
    __shared__ unsigned short lw1[16384];       // 32 KB
    __shared__ unsigned short lw2[8192];        // 16 KB
    __shared__ unsigned short bounce[4][2048];  // 4 waves x 4 KB
    {
        int tid = threadIdx.x;
        const f32x4* s1 = (const f32x4*)fW1;
        f32x4* d1 = (f32x4*)lw1;
        #pragma unroll
        for (int i = 0; i < 8; ++i) d1[i * 256 + tid] = s1[i * 256 + tid];
        const f32x4* s2 = (const f32x4*)fW2;
        f32x4* d2 = (f32x4*)lw2;
        #pragma unroll
        for (int i = 0; i < 4; ++i) d2[i * 256 + tid] = s2[i * 256 + tid];
    }
    __syncthreads();
    const int w = threadIdx.x >> 6, l = threadIdx.x & 63;
    const int lr = l & 15, lg = l >> 4;
    float b1v[8], b2v[4], wev[4];
    #pragma unroll
    for (int n = 0; n < 8; ++n) b1v[n] = b1[n * 16 + lr];
    #pragma unroll
    for (int n = 0; n < 4; ++n) { b2v[n] = b2[n * 16 + lr]; wev[n] = weff[n * 16 + lr]; }
    const float bo = b_out[0];

    for (int t = blockIdx.x; t < NSAMP / 64; t += 512) {
        const int s0 = t * 64 + w * 16;
        f32x4 acc1[8];
        #pragma unroll
        for (int n = 0; n < 8; ++n) acc1[n] = (f32x4){0.f, 0.f, 0.f, 0.f};
        const unsigned short* arow = M + (size_t)(s0 + lr) * 128 + lg * 8;
        #pragma unroll
        for (int ks = 0; ks < 4; ++ks) {
            bf16x8 af = *(const bf16x8*)(arow + ks * 32);
            #pragma unroll
            for (int n = 0; n < 8; ++n) {
                bf16x8 bf = *(const bf16x8*)&lw1[((ks * 8 + n) * 64 + l) * 8];
                acc1[n] = __builtin_amdgcn_mfma_f32_16x16x32_bf16(af, bf, acc1[n], 0, 0, 0);
            }
        }
        #pragma unroll
        for (int n = 0; n < 8; ++n) {
            #pragma unroll
            for (int rr = 0; rr < 4; ++rr) {
                float g = fmaxf(acc1[n][rr] + b1v[n], 0.f);
                int row = lg * 4 + rr, col = n * 16 + lr;
                int boff = row * 256 + ((col * 2) ^ ((row & 7) << 4));
                bounce[w][boff >> 1] = f2bf(g);
            }
        }
        f32x4 acc2[4];
        #pragma unroll
        for (int n = 0; n < 4; ++n) acc2[n] = (f32x4){0.f, 0.f, 0.f, 0.f};
        #pragma unroll
        for (int ks = 0; ks < 4; ++ks) {
            int roff = lr * 256 + ((ks * 64 + lg * 16) ^ ((lr & 7) << 4));
            bf16x8 af2 = *(const bf16x8*)((const char*)&bounce[w][0] + roff);
            #pragma unroll
            for (int n = 0; n < 4; ++n) {
                bf16x8 bf = *(const bf16x8*)&lw2[((ks * 4 + n) * 64 + l) * 8];
                acc2[n] = __builtin_amdgcn_mfma_f32_16x16x32_bf16(af2, bf, acc2[n], 0, 0, 0);
            }
        }
        float p0 = 0.f, p1 = 0.f, p2 = 0.f, p3 = 0.f;
        #pragma unroll
        for (int n = 0; n < 4; ++n) {
            p0 += fmaxf(acc2[n][0] + b2v[n], 0.f) * wev[n];
            p1 += fmaxf(acc2[n][1] + b2v[n], 0.f) * wev[n];
            p2 += fmaxf(acc2[n][2] + b2v[n], 0.f) * wev[n];
            p3 += fmaxf(acc2[n][3] + b2v[n], 0.f) * wev[n];
        }
        #pragma unroll
        for (int m = 1; m < 16; m <<= 1) {
            p0 += __shfl_xor(p0, m);
            p1 += __shfl_xor(p1, m);
            p2 += __shfl_xor(p2, m);
            p3 += __shfl_xor(p3, m);
        }
        float s0f = 1.f / (1.f + expf(-(p0 + bo)));
        float s1f = 1.f / (1.f + expf(-(p1 + bo)));
        float s2f = 1.f / (1.f + expf(-(p2 + bo)));
        float s3f = 1.f / (1.f + expf(-(p3 + bo)));
        if (lr < 4) {
            float v = (lr == 0) ? s0f : (lr == 1) ? s1f : (lr == 2) ? s2f : s3f;
            out[s0 + lg * 4 + lr] = v;
        }
    }
}

// ---------------- host launcher ----------------
extern "C" void kernel_launch(void* const* d_in, const int* in_sizes, int n_in,
                              void* d_out, int out_size, void* d_ws, size_t ws_size,
                              hipStream_t stream) {
    const float* combined = (const float*)d_in[0];
    const float* W_in  = (const float*)d_in[1];
    const float* b_in  = (const float*)d_in[2];
    const float* W1    = (const float*)d_in[3];
    const float* b1    = (const float*)d_in[4];
    const float* W2    = (const float*)d_in[5];
    const float* b2    = (const float*)d_in[6];
    const float* W_out = (const float*)d_in[7];
    const float* b_out = (const float*)d_in[8];
    float* out = (float*)d_out;

    char* ws = (char*)d_ws;
    unsigned short* M    = (unsigned short*)(ws + WS_M);
    unsigned short* fWin = (unsigned short*)(ws + WS_WIN);
    unsigned short* fW1  = (unsigned short*)(ws + WS_W1);
    unsigned short* fW2  = (unsigned short*)(ws + WS_W2);
    float* weff          = (float*)(ws + WS_WEFF);

    prep_kernel<<<(65536 + 16384 + 8192 + 64 + 255) / 256, 256, 0, stream>>>(
        W_in, W1, W2, W_out, fWin, fW1, fW2, weff);
    kA<<<256, 1024, 0, stream>>>(combined, fWin, b_in, M);
    kB<<<512, 256, 0, stream>>>(M, fW1, fW2, weff, b1, b2, b_out, out);
}